// Round 8
// baseline (207.391 us; speedup 1.0000x reference)
//
#include <hip/hip_runtime.h>
#include <math.h>

#define NB 2
#define NL 2048
#define NK 32
#define NODE_F 128
#define EDGE_F 128

// output layout (float32 elements)
#define OFF_HV   0
#define OFF_HE   (NB*NL*NODE_F)                 // 524288
#define OFF_EIDX (OFF_HE + NB*NL*NK*EDGE_F)     // 17301504
#define OFF_X    (OFF_EIDX + NB*NL*NK)          // 17432576

typedef __attribute__((ext_vector_type(8))) short v8s;
typedef __attribute__((ext_vector_type(4))) float v4f;

__device__ __forceinline__ short f2bf(float f) {
    unsigned u = __float_as_uint(f);
    unsigned r = u + 0x7fffu + ((u >> 16) & 1u);
    return (short)(r >> 16);
}

// ---------------- helpers ----------------
__device__ __forceinline__ void cross3(const float a[3], const float b[3], float c[3]) {
    c[0] = a[1]*b[2] - a[2]*b[1];
    c[1] = a[2]*b[0] - a[0]*b[2];
    c[2] = a[0]*b[1] - a[1]*b[0];
}
__device__ __forceinline__ float dot3(const float a[3], const float b[3]) {
    return a[0]*b[0] + a[1]*b[1] + a[2]*b[2];
}
__device__ float dihedral_f(const float p0[3], const float p1[3],
                            const float p2[3], const float p3[3]) {
    float u0[3], u1[3], u2[3];
    for (int d = 0; d < 3; d++) {
        u0[d] = p2[d] - p1[d];
        u1[d] = p0[d] - p1[d];
        u2[d] = p3[d] - p2[d];
    }
    float n1[3], n2[3], c12[3];
    cross3(u0, u1, n1);
    cross3(u0, u2, n2);
    cross3(u1, u2, c12);
    float l1 = sqrtf(dot3(n1, n1));
    float l2 = sqrtf(dot3(n2, n2));
    float cosang = dot3(n1, n2) / (l1 * l2);
    float s = dot3(c12, u0);
    float sgn = (s > 0.f) ? 1.f : ((s < 0.f) ? -1.f : 0.f);
    float r = sgn * acosf(cosang);
    return isnan(r) ? 0.f : r;
}

// ---------------- kernel 0: W_edge RBF rows -> bf16 MFMA-fragment order ----------------
__global__ void wconv_kernel(const float* __restrict__ We, short* __restrict__ WTf) {
    int t = blockIdx.x * 256 + threadIdx.x;
    if (t >= 13 * 8 * 64) return;
    int lane = t & 63;
    int nt = (t >> 6) & 7;
    int ch = t >> 9;
    int n = nt * 16 + (lane & 15);
    int kbase = ch * 32 + (lane >> 4) * 8;
    short* dst = WTf + (size_t)t * 8;
#pragma unroll
    for (int j = 0; j < 8; j++) {
        int k = kbase + j;
        float f = (k < 400) ? We[(65 + k) * 128 + n] : 0.f;
        dst[j] = f2bf(f);
    }
}

// ---------------- kernel 1: X5 prep + planar Ca + X passthrough ----------------
__global__ void prep_kernel(const float* __restrict__ X, float* __restrict__ X5,
                            float* __restrict__ Cax, float* __restrict__ Cay,
                            float* __restrict__ Caz, float* __restrict__ out) {
    int row = blockIdx.x * blockDim.x + threadIdx.x;
    if (row >= NB * NL) return;
    float v[12];
#pragma unroll
    for (int t = 0; t < 12; t++) v[t] = X[row * 12 + t];
#pragma unroll
    for (int t = 0; t < 12; t++) out[OFF_X + row * 12 + t] = v[t];
    Cax[row] = v[3]; Cay[row] = v[4]; Caz[row] = v[5];
    float bv[3], cv[3], cr[3];
    for (int d = 0; d < 3; d++) { bv[d] = v[3+d] - v[d]; cv[d] = v[6+d] - v[3+d]; }
    cross3(bv, cv, cr);
    float* x5 = X5 + row * 15;
#pragma unroll
    for (int t = 0; t < 12; t++) x5[t] = v[t];
    for (int d = 0; d < 3; d++)
        x5[12 + d] = -0.58273431f * cr[d] + 0.56802827f * bv[d] - 0.54067466f * cv[d] + v[3+d];
}

// ---------------- kernel 2: KNN v7 — zero LDS, 32 f32 distance registers ----------------
__global__ __launch_bounds__(256) void knn7_kernel(const float* __restrict__ Cax,
                                                   const float* __restrict__ Cay,
                                                   const float* __restrict__ Caz,
                                                   const float* __restrict__ mask,
                                                   int* __restrict__ EidxW,
                                                   float* __restrict__ out) {
    int tid = threadIdx.x;
    int w = tid >> 6, l = tid & 63;
    int row = blockIdx.x * 4 + w;     // 4 rows/block, same batch (NL%4==0)
    int b = row / NL;
    int base = b * NL;
    const float* mrow = mask + base;

    float cx = Cax[row], cy = Cay[row], cz = Caz[row];
    float mi = mrow[row - base];

    float K[32];
    float lmax = 0.0f;
#pragma unroll
    for (int t = 0; t < 32; t++) {
        int j = t * 64 + l;
        float dx = __fsub_rn(cx, Cax[base + j]);
        float dy = __fsub_rn(cy, Cay[base + j]);
        float dz = __fsub_rn(cz, Caz[base + j]);
        float ss = __fadd_rn(__fadd_rn(__fadd_rn(__fmul_rn(dx, dx), __fmul_rn(dy, dy)),
                                       __fmul_rn(dz, dz)), 1e-6f);
        float d = __fmul_rn(__fmul_rn(mi, mrow[j]), __fsqrt_rn(ss));
        K[t] = d;
        lmax = fmaxf(lmax, d);
    }
#pragma unroll
    for (int s = 1; s < 64; s <<= 1) lmax = fmaxf(lmax, __shfl_xor(lmax, s, 64));
#pragma unroll
    for (int t = 0; t < 32; t++) {
        int j = t * 64 + l;
        float m2 = __fmul_rn(mi, mrow[j]);
        K[t] = __fadd_rn(K[t], __fmul_rn(__fmul_rn(2.0f, __fsub_rn(1.0f, m2)), lmax));
    }

    const float INF = __int_as_float(0x7F800000);
    int selj = 0;
#pragma unroll 1
    for (int r = 0; r < NK; r++) {
        float bd = K[0];
        int bt = 0;
#pragma unroll
        for (int t = 1; t < 32; t++) {
            bool c = K[t] < bd;
            bd = c ? K[t] : bd;
            bt = c ? t : bt;
        }
        unsigned long long best =
            (((unsigned long long)__float_as_uint(bd)) << 32) |
            (unsigned)((bt << 6) | l);
#pragma unroll
        for (int s = 1; s < 64; s <<= 1) {
            unsigned long long o = __shfl_xor(best, s, 64);
            best = (o < best) ? o : best;
        }
        int bj = (int)(best & 0xFFFFFFFFu);
        int bjs = __builtin_amdgcn_readfirstlane(bj);
        if (l == r) selj = bj;
        bool me = (l == (bjs & 63));
        int btg = bjs >> 6;
#pragma unroll
        for (int t = 0; t < 32; t++)
            K[t] = (me && t == btg) ? INF : K[t];
    }
    if (l < NK) {
        EidxW[row * NK + l] = selj;
        out[OFF_EIDX + row * NK + l] = (float)selj;
    }
}

// ---------------- kernel 3: node features + LN (one wave per row, shfl-only) ----------------
__global__ __launch_bounds__(256) void node2_kernel(const int* __restrict__ S,
                                                    const float* __restrict__ BB,
                                                    const float* __restrict__ SC,
                                                    const float* __restrict__ Wn,
                                                    const float* __restrict__ bn,
                                                    const float* __restrict__ gn,
                                                    const float* __restrict__ betan,
                                                    float* __restrict__ out) {
    int tid = threadIdx.x;
    int w = tid >> 6, l = tid & 63;
    int row = blockIdx.x * 4 + w;
    int f0 = l, f1 = 64 + l;
    int s = S[row];
    float a0 = bn[f0] + Wn[s * NODE_F + f0];
    float a1 = bn[f1] + Wn[s * NODE_F + f1];
#pragma unroll
    for (int t = 0; t < 6; t++) {
        float x = BB[row * 6 + t];
        a0 += x * Wn[(21 + t) * NODE_F + f0];
        a1 += x * Wn[(21 + t) * NODE_F + f1];
    }
#pragma unroll
    for (int t = 0; t < 8; t++) {
        float x = SC[row * 8 + t];
        a0 += x * Wn[(27 + t) * NODE_F + f0];
        a1 += x * Wn[(27 + t) * NODE_F + f1];
    }
    float sm = a0 + a1;
#pragma unroll
    for (int st = 1; st < 64; st <<= 1) sm += __shfl_xor(sm, st, 64);
    float mean = sm * (1.0f / 128.0f);
    float d0 = a0 - mean, d1 = a1 - mean;
    float q = d0 * d0 + d1 * d1;
#pragma unroll
    for (int st = 1; st < 64; st <<= 1) q += __shfl_xor(q, st, 64);
    float rstd = 1.0f / sqrtf(q * (1.0f / 128.0f) + 1e-5f);
    out[OFF_HV + row * NODE_F + f0] = d0 * rstd * gn[f0] + betan[f0];
    out[OFF_HV + row * NODE_F + f1] = d1 * rstd * gn[f1] + betan[f1];
}

// ---------------- kernel 4: edge3 — barrier-free K-loop, direct global B-frags, exp2 RBF ----------------
// block = 64 edges, 256 threads = 4 waves. After one feature barrier, waves run
// independently: per chunk, A-frag via exp2(A*e^2+B_j*e+C_j), B-frag straight from
// WTf (global dwordx4, L1/L2-hit: identical stream for all waves/blocks), 8 MFMA.
__global__ __launch_bounds__(256) void edge3_kernel(const float* __restrict__ X5,
                                                    const int* __restrict__ Eidx,
                                                    const int* __restrict__ chain,
                                                    const float* __restrict__ We,
                                                    const float* __restrict__ be,
                                                    const float* __restrict__ ge,
                                                    const float* __restrict__ betae,
                                                    const short* __restrict__ WTf,
                                                    float* __restrict__ out) {
    __shared__ float sXi[2][15];
    __shared__ float sXj[64][17];   // 17-float rows: odd stride -> no bank conflicts
    __shared__ int sJ[64];
    __shared__ int sPos[64];
    __shared__ float sEt[64], sPhi[64], sPsi[64];
    __shared__ float sDn[25][64];
    __shared__ float sRow[6][128];

    int tid = threadIdx.x;
    int e0 = blockIdx.x * 64;
    int b = e0 / (NL * NK);
    int i0 = (e0 / NK) % NL;

    if (tid < 64) sJ[tid] = Eidx[e0 + tid];
    if (tid < 30) sXi[tid / 15][tid % 15] = X5[(b * NL + i0 + tid / 15) * 15 + (tid % 15)];
    for (int t = tid; t < 6 * 128; t += 256) {
        int rr = t >> 7, n2 = t & 127;
        float v;
        if (rr < 3) v = We[(465 + rr) * 128 + n2];
        else if (rr == 3) v = be[n2];
        else if (rr == 4) v = ge[n2];
        else v = betae[n2];
        sRow[rr][n2] = v;
    }
    __syncthreads();
    for (int t = tid; t < 64 * 15; t += 256) {
        int e = t / 15, c2 = t % 15;
        sXj[e][c2] = X5[(b * NL + sJ[e]) * 15 + c2];
    }
    if (tid < 64) {
        int e = tid;
        int i = i0 + (e >> 5);
        int j = sJ[e];
        int off = j - i + 32;
        off = off < 0 ? 0 : (off > 64 ? 64 : off);
        sPos[e] = off;
        sEt[e] = (chain[b * NL + j] == chain[b * NL + i]) ? 2.0f : 1.0f;
    }
    __syncthreads();
    for (int t = tid; t < 1600; t += 256) {
        int p = t >> 6, e = t & 63;
        int a = p / 5, c2 = p - a * 5;
        const float* xi = &sXi[e >> 5][a * 3];
        const float* xj = &sXj[e][c2 * 3];
        float dx = xi[0] - xj[0], dy = xi[1] - xj[1], dz = xi[2] - xj[2];
        sDn[p][e] = sqrtf(dx * dx + dy * dy + dz * dz + 1e-6f);
    }
    if (tid < 64) {
        int e = tid;
        const float* xi = sXi[e >> 5];
        const float* xj = sXj[e];
        sPhi[e] = dihedral_f(&xi[6], &xj[0], &xj[3], &xj[6]);
        sPsi[e] = dihedral_f(&xi[0], &xi[3], &xi[6], &xj[0]);
    }
    __syncthreads();   // the ONLY barrier before the epilogue

    int lane = tid & 63, w = tid >> 6;
    int c = lane & 15, kq = lane >> 4;
    int eA = w * 16 + c;
    float hf = (float)(kq & 1);
    v4f acc[8];
#pragma unroll
    for (int nt = 0; nt < 8; nt++) acc[nt] = (v4f){0.f, 0.f, 0.f, 0.f};

    // RBF: exp(-0.64*(d-mu)^2) = exp2(A*(e-muj)^2), A = -0.64*log2(e)
    const float Ac = -0.92332482616893658f;
#pragma unroll 1
    for (int ch = 0; ch < 13; ch++) {
        int pair = 2 * ch + (kq >> 1);
        float d = sDn[pair < 25 ? pair : 24][eA];
        float ee = __fmaf_rn(hf, -10.666666666666666f, d);   // e = d - (kq&1)*32/3
        float t1 = Ac * ee * ee;
        v8s a;
#pragma unroll
        for (int j = 0; j < 8; j++) {
            const float muj = (float)j * (20.0f / 15.0f);
            const float Bj = -2.0f * Ac * muj;
            const float Cj = Ac * muj * muj;
            float y = __fmaf_rn(Bj, ee, t1) + Cj;
            float rv = exp2f(y);
            a[j] = (pair < 25) ? f2bf(rv) : (short)0;
        }
        const v8s* gb = (const v8s*)(WTf + (((size_t)ch * 8 * 64 + lane) << 3));
#pragma unroll
        for (int nt = 0; nt < 8; nt++) {
            v8s bfr = gb[nt * 64];
            acc[nt] = __builtin_amdgcn_mfma_f32_16x16x32_bf16(a, bfr, acc[nt], 0, 0, 0);
        }
    }

    // epilogue: C/D layout col n = nt*16 + (lane&15), row m = kq*4 + r
#pragma unroll
    for (int r = 0; r < 4; r++) {
        int m = kq * 4 + r;
        int e = w * 16 + m;
        float ph = sPhi[e], ps = sPsi[e], et = sEt[e];
        int pos = sPos[e];
        float vals[8];
        float s = 0.f, q2 = 0.f;
#pragma unroll
        for (int nt = 0; nt < 8; nt++) {
            int n = nt * 16 + c;
            float v = acc[nt][r] + sRow[3][n] + We[pos * 128 + n]
                    + et * sRow[0][n] + ph * sRow[1][n] + ps * sRow[2][n];
            vals[nt] = v;
            s += v;
            q2 += v * v;
        }
#pragma unroll
        for (int s2 = 1; s2 < 16; s2 <<= 1) {
            s  += __shfl_xor(s,  s2, 64);
            q2 += __shfl_xor(q2, s2, 64);
        }
        float mean = s * (1.0f / 128.0f);
        float var = q2 * (1.0f / 128.0f) - mean * mean;
        float rstd = rsqrtf(var + 1e-5f);
#pragma unroll
        for (int nt = 0; nt < 8; nt++) {
            int n = nt * 16 + c;
            out[OFF_HE + (size_t)(e0 + e) * 128 + n] =
                (vals[nt] - mean) * rstd * sRow[4][n] + sRow[5][n];
        }
    }
}

// ---------------- launch ----------------
extern "C" void kernel_launch(void* const* d_in, const int* in_sizes, int n_in,
                              void* d_out, int out_size, void* d_ws, size_t ws_size,
                              hipStream_t stream) {
    (void)in_sizes; (void)n_in; (void)out_size; (void)ws_size;
    const float* X    = (const float*)d_in[0];
    const int*   S    = (const int*)d_in[1];
    const float* BB   = (const float*)d_in[2];
    const float* SC   = (const float*)d_in[3];
    const int*   chain= (const int*)d_in[4];
    const float* mask = (const float*)d_in[5];
    const float* Wn   = (const float*)d_in[6];
    const float* bn   = (const float*)d_in[7];
    const float* gn   = (const float*)d_in[8];
    const float* betan= (const float*)d_in[9];
    const float* We   = (const float*)d_in[10];
    const float* be   = (const float*)d_in[11];
    const float* ge   = (const float*)d_in[12];
    const float* betae= (const float*)d_in[13];
    float* out = (float*)d_out;

    char* ws = (char*)d_ws;
    int*   EidxW = (int*)ws;                                  // 524288 B
    float* X5    = (float*)(ws + 524288);                     // 245760 B (ends 770048)
    short* WTf   = (short*)(ws + 770048);                     // 106496 B (ends 876544)
    float* Cax   = (float*)(ws + 876544);                     // 16384 B
    float* Cay   = (float*)(ws + 892928);                     // 16384 B
    float* Caz   = (float*)(ws + 909312);                     // 16384 B (ends 925696)

    hipLaunchKernelGGL(wconv_kernel, dim3(26), dim3(256), 0, stream, We, WTf);
    hipLaunchKernelGGL(prep_kernel, dim3((NB * NL + 255) / 256), dim3(256), 0, stream,
                       X, X5, Cax, Cay, Caz, out);
    hipLaunchKernelGGL(knn7_kernel, dim3(NB * NL / 4), dim3(256), 0, stream,
                       Cax, Cay, Caz, mask, EidxW, out);
    hipLaunchKernelGGL(node2_kernel, dim3(NB * NL / 4), dim3(256), 0, stream,
                       S, BB, SC, Wn, bn, gn, betan, out);
    hipLaunchKernelGGL(edge3_kernel, dim3(NB * NL * NK / 64), dim3(256), 0, stream,
                       X5, EidxW, chain, We, be, ge, betae, WTf, out);
}

// Round 9
// 205.333 us; speedup vs baseline: 1.0100x; 1.0100x over previous
//
#include <hip/hip_runtime.h>
#include <math.h>

#define NB 2
#define NL 2048
#define NK 32
#define NODE_F 128
#define EDGE_F 128

// output layout (float32 elements)
#define OFF_HV   0
#define OFF_HE   (NB*NL*NODE_F)                 // 524288
#define OFF_EIDX (OFF_HE + NB*NL*NK*EDGE_F)     // 17301504
#define OFF_X    (OFF_EIDX + NB*NL*NK)          // 17432576

typedef __attribute__((ext_vector_type(8))) short v8s;
typedef __attribute__((ext_vector_type(4))) float v4f;

__device__ __forceinline__ short f2bf(float f) {
    unsigned u = __float_as_uint(f);
    unsigned r = u + 0x7fffu + ((u >> 16) & 1u);
    return (short)(r >> 16);
}

#if __has_builtin(__builtin_amdgcn_exp2f)
#define EXP2F(x) __builtin_amdgcn_exp2f(x)
#else
#define EXP2F(x) __expf((x) * 0.6931471805599453f)
#endif

// pack top halves of two f32 bit-patterns (truncating f32->bf16) into one u32
__device__ __forceinline__ unsigned bfpack(float f0, float f1) {
    unsigned u0 = __float_as_uint(f0), u1 = __float_as_uint(f1);
#if __has_builtin(__builtin_amdgcn_perm)
    return __builtin_amdgcn_perm(u1, u0, 0x07060302u);  // {u1.hi16, u0.hi16}
#else
    return (u1 & 0xFFFF0000u) | (u0 >> 16);
#endif
}

// ---------------- helpers ----------------
__device__ __forceinline__ void cross3(const float a[3], const float b[3], float c[3]) {
    c[0] = a[1]*b[2] - a[2]*b[1];
    c[1] = a[2]*b[0] - a[0]*b[2];
    c[2] = a[0]*b[1] - a[1]*b[0];
}
__device__ __forceinline__ float dot3(const float a[3], const float b[3]) {
    return a[0]*b[0] + a[1]*b[1] + a[2]*b[2];
}
__device__ float dihedral_f(const float p0[3], const float p1[3],
                            const float p2[3], const float p3[3]) {
    float u0[3], u1[3], u2[3];
    for (int d = 0; d < 3; d++) {
        u0[d] = p2[d] - p1[d];
        u1[d] = p0[d] - p1[d];
        u2[d] = p3[d] - p2[d];
    }
    float n1[3], n2[3], c12[3];
    cross3(u0, u1, n1);
    cross3(u0, u2, n2);
    cross3(u1, u2, c12);
    float l1 = sqrtf(dot3(n1, n1));
    float l2 = sqrtf(dot3(n2, n2));
    float cosang = dot3(n1, n2) / (l1 * l2);
    float s = dot3(c12, u0);
    float sgn = (s > 0.f) ? 1.f : ((s < 0.f) ? -1.f : 0.f);
    float r = sgn * acosf(cosang);
    return isnan(r) ? 0.f : r;
}

// ---------------- kernel 0: W_edge RBF rows -> bf16 MFMA-fragment order ----------------
__global__ void wconv_kernel(const float* __restrict__ We, short* __restrict__ WTf) {
    int t = blockIdx.x * 256 + threadIdx.x;
    if (t >= 13 * 8 * 64) return;
    int lane = t & 63;
    int nt = (t >> 6) & 7;
    int ch = t >> 9;
    int n = nt * 16 + (lane & 15);
    int kbase = ch * 32 + (lane >> 4) * 8;
    short* dst = WTf + (size_t)t * 8;
#pragma unroll
    for (int j = 0; j < 8; j++) {
        int k = kbase + j;
        float f = (k < 400) ? We[(65 + k) * 128 + n] : 0.f;
        dst[j] = f2bf(f);
    }
}

// ---------------- kernel 1: X5 prep + planar Ca + X passthrough ----------------
__global__ void prep_kernel(const float* __restrict__ X, float* __restrict__ X5,
                            float* __restrict__ Cax, float* __restrict__ Cay,
                            float* __restrict__ Caz, float* __restrict__ out) {
    int row = blockIdx.x * blockDim.x + threadIdx.x;
    if (row >= NB * NL) return;
    float v[12];
#pragma unroll
    for (int t = 0; t < 12; t++) v[t] = X[row * 12 + t];
#pragma unroll
    for (int t = 0; t < 12; t++) out[OFF_X + row * 12 + t] = v[t];
    Cax[row] = v[3]; Cay[row] = v[4]; Caz[row] = v[5];
    float bv[3], cv[3], cr[3];
    for (int d = 0; d < 3; d++) { bv[d] = v[3+d] - v[d]; cv[d] = v[6+d] - v[3+d]; }
    cross3(bv, cv, cr);
    float* x5 = X5 + row * 15;
#pragma unroll
    for (int t = 0; t < 12; t++) x5[t] = v[t];
    for (int d = 0; d < 3; d++)
        x5[12 + d] = -0.58273431f * cr[d] + 0.56802827f * bv[d] - 0.54067466f * cv[d] + v[3+d];
}

// ---------------- kernel 2: KNN v7 — zero LDS, 32 f32 distance registers ----------------
__global__ __launch_bounds__(256) void knn7_kernel(const float* __restrict__ Cax,
                                                   const float* __restrict__ Cay,
                                                   const float* __restrict__ Caz,
                                                   const float* __restrict__ mask,
                                                   int* __restrict__ EidxW,
                                                   float* __restrict__ out) {
    int tid = threadIdx.x;
    int w = tid >> 6, l = tid & 63;
    int row = blockIdx.x * 4 + w;     // 4 rows/block, same batch (NL%4==0)
    int b = row / NL;
    int base = b * NL;
    const float* mrow = mask + base;

    float cx = Cax[row], cy = Cay[row], cz = Caz[row];
    float mi = mrow[row - base];

    float K[32];
    float lmax = 0.0f;
#pragma unroll
    for (int t = 0; t < 32; t++) {
        int j = t * 64 + l;
        float dx = __fsub_rn(cx, Cax[base + j]);
        float dy = __fsub_rn(cy, Cay[base + j]);
        float dz = __fsub_rn(cz, Caz[base + j]);
        float ss = __fadd_rn(__fadd_rn(__fadd_rn(__fmul_rn(dx, dx), __fmul_rn(dy, dy)),
                                       __fmul_rn(dz, dz)), 1e-6f);
        float d = __fmul_rn(__fmul_rn(mi, mrow[j]), __fsqrt_rn(ss));
        K[t] = d;
        lmax = fmaxf(lmax, d);
    }
#pragma unroll
    for (int s = 1; s < 64; s <<= 1) lmax = fmaxf(lmax, __shfl_xor(lmax, s, 64));
#pragma unroll
    for (int t = 0; t < 32; t++) {
        int j = t * 64 + l;
        float m2 = __fmul_rn(mi, mrow[j]);
        K[t] = __fadd_rn(K[t], __fmul_rn(__fmul_rn(2.0f, __fsub_rn(1.0f, m2)), lmax));
    }

    const float INF = __int_as_float(0x7F800000);
    int selj = 0;
#pragma unroll 1
    for (int r = 0; r < NK; r++) {
        float bd = K[0];
        int bt = 0;
#pragma unroll
        for (int t = 1; t < 32; t++) {
            bool c = K[t] < bd;
            bd = c ? K[t] : bd;
            bt = c ? t : bt;
        }
        unsigned long long best =
            (((unsigned long long)__float_as_uint(bd)) << 32) |
            (unsigned)((bt << 6) | l);
#pragma unroll
        for (int s = 1; s < 64; s <<= 1) {
            unsigned long long o = __shfl_xor(best, s, 64);
            best = (o < best) ? o : best;
        }
        int bj = (int)(best & 0xFFFFFFFFu);
        int bjs = __builtin_amdgcn_readfirstlane(bj);
        if (l == r) selj = bj;
        bool me = (l == (bjs & 63));
        int btg = bjs >> 6;
#pragma unroll
        for (int t = 0; t < 32; t++)
            K[t] = (me && t == btg) ? INF : K[t];
    }
    if (l < NK) {
        EidxW[row * NK + l] = selj;
        out[OFF_EIDX + row * NK + l] = (float)selj;
    }
}

// ---------------- kernel 3: node features + LN (one wave per row, shfl-only) ----------------
__global__ __launch_bounds__(256) void node2_kernel(const int* __restrict__ S,
                                                    const float* __restrict__ BB,
                                                    const float* __restrict__ SC,
                                                    const float* __restrict__ Wn,
                                                    const float* __restrict__ bn,
                                                    const float* __restrict__ gn,
                                                    const float* __restrict__ betan,
                                                    float* __restrict__ out) {
    int tid = threadIdx.x;
    int w = tid >> 6, l = tid & 63;
    int row = blockIdx.x * 4 + w;
    int f0 = l, f1 = 64 + l;
    int s = S[row];
    float a0 = bn[f0] + Wn[s * NODE_F + f0];
    float a1 = bn[f1] + Wn[s * NODE_F + f1];
#pragma unroll
    for (int t = 0; t < 6; t++) {
        float x = BB[row * 6 + t];
        a0 += x * Wn[(21 + t) * NODE_F + f0];
        a1 += x * Wn[(21 + t) * NODE_F + f1];
    }
#pragma unroll
    for (int t = 0; t < 8; t++) {
        float x = SC[row * 8 + t];
        a0 += x * Wn[(27 + t) * NODE_F + f0];
        a1 += x * Wn[(27 + t) * NODE_F + f1];
    }
    float sm = a0 + a1;
#pragma unroll
    for (int st = 1; st < 64; st <<= 1) sm += __shfl_xor(sm, st, 64);
    float mean = sm * (1.0f / 128.0f);
    float d0 = a0 - mean, d1 = a1 - mean;
    float q = d0 * d0 + d1 * d1;
#pragma unroll
    for (int st = 1; st < 64; st <<= 1) q += __shfl_xor(q, st, 64);
    float rstd = 1.0f / sqrtf(q * (1.0f / 128.0f) + 1e-5f);
    out[OFF_HV + row * NODE_F + f0] = d0 * rstd * gn[f0] + betan[f0];
    out[OFF_HV + row * NODE_F + f1] = d1 * rstd * gn[f1] + betan[f1];
}

// ---------------- kernel 4: edge4 — registerized K-loop: LDS hoisted, loads-first, fast exp/pack ----------------
__global__ __launch_bounds__(256) void edge4_kernel(const float* __restrict__ X5,
                                                    const int* __restrict__ Eidx,
                                                    const int* __restrict__ chain,
                                                    const float* __restrict__ We,
                                                    const float* __restrict__ be,
                                                    const float* __restrict__ ge,
                                                    const float* __restrict__ betae,
                                                    const short* __restrict__ WTf,
                                                    float* __restrict__ out) {
    __shared__ float sXi[2][15];
    __shared__ float sXj[64][17];   // odd stride: no bank conflicts
    __shared__ int sJ[64];
    __shared__ int sPos[64];
    __shared__ float sEt[64], sPhi[64], sPsi[64];
    __shared__ float sDn[25][64];
    __shared__ float sRow[6][128];

    int tid = threadIdx.x;
    int e0 = blockIdx.x * 64;
    int b = e0 / (NL * NK);
    int i0 = (e0 / NK) % NL;

    if (tid < 64) sJ[tid] = Eidx[e0 + tid];
    if (tid < 30) sXi[tid / 15][tid % 15] = X5[(b * NL + i0 + tid / 15) * 15 + (tid % 15)];
    for (int t = tid; t < 6 * 128; t += 256) {
        int rr = t >> 7, n2 = t & 127;
        float v;
        if (rr < 3) v = We[(465 + rr) * 128 + n2];
        else if (rr == 3) v = be[n2];
        else if (rr == 4) v = ge[n2];
        else v = betae[n2];
        sRow[rr][n2] = v;
    }
    __syncthreads();
    for (int t = tid; t < 64 * 15; t += 256) {
        int e = t / 15, c2 = t % 15;
        sXj[e][c2] = X5[(b * NL + sJ[e]) * 15 + c2];
    }
    if (tid < 64) {
        int e = tid;
        int i = i0 + (e >> 5);
        int j = sJ[e];
        int off = j - i + 32;
        off = off < 0 ? 0 : (off > 64 ? 64 : off);
        sPos[e] = off;
        sEt[e] = (chain[b * NL + j] == chain[b * NL + i]) ? 2.0f : 1.0f;
    }
    __syncthreads();
    for (int t = tid; t < 1600; t += 256) {
        int p = t >> 6, e = t & 63;
        int a = p / 5, c2 = p - a * 5;
        const float* xi = &sXi[e >> 5][a * 3];
        const float* xj = &sXj[e][c2 * 3];
        float dx = xi[0] - xj[0], dy = xi[1] - xj[1], dz = xi[2] - xj[2];
        sDn[p][e] = sqrtf(dx * dx + dy * dy + dz * dz + 1e-6f);
    }
    if (tid < 64) {
        int e = tid;
        const float* xi = sXi[e >> 5];
        const float* xj = sXj[e];
        sPhi[e] = dihedral_f(&xi[6], &xj[0], &xj[3], &xj[6]);
        sPsi[e] = dihedral_f(&xi[0], &xi[3], &xi[6], &xj[0]);
    }
    __syncthreads();   // only barrier before epilogue

    int lane = tid & 63, w = tid >> 6;
    int c = lane & 15, kq = lane >> 4;
    int eA = w * 16 + c;
    int p0 = kq >> 1;
    float hf = (float)(kq & 1);

    // hoist all per-chunk e-values into registers (one lgkm wait; LDS leaves the loop)
    float ech[13];
#pragma unroll
    for (int ch = 0; ch < 13; ch++) {
        int pair = 2 * ch + p0;
        float d = sDn[pair < 25 ? pair : 24][eA];
        ech[ch] = __fmaf_rn(hf, -10.666666666666666f, d);   // e = d - (kq&1)*32/3
    }
    bool tailInvalid = (p0 == 1);   // ch==12 -> pair 25 (k >= 400) for kq >= 2

    v4f acc[8];
#pragma unroll
    for (int nt = 0; nt < 8; nt++) acc[nt] = (v4f){0.f, 0.f, 0.f, 0.f};

    // rbf = exp2(Ac*(e-muj)^2), Ac = -0.64*log2(e); y_j = fma(Bj, e, t1) + Cj
    const float Ac = -0.92332482616893658f;
#pragma unroll 2
    for (int ch = 0; ch < 13; ch++) {
        // B-fragments FIRST: VMEM latency overlaps the register-only A-generation
        v8s bfr[8];
        const v8s* gb = (const v8s*)WTf + ((size_t)ch * 512 + lane);
#pragma unroll
        for (int nt = 0; nt < 8; nt++) bfr[nt] = gb[nt * 64];

        float ee = ech[ch];
        float t1 = Ac * ee * ee;
        union { unsigned u[4]; v8s v; } au;
#pragma unroll
        for (int jp = 0; jp < 4; jp++) {
            const float mu0 = (float)(2 * jp) * (20.0f / 15.0f);
            const float mu1 = (float)(2 * jp + 1) * (20.0f / 15.0f);
            const float B0 = -2.0f * Ac * mu0, C0 = Ac * mu0 * mu0;
            const float B1 = -2.0f * Ac * mu1, C1 = Ac * mu1 * mu1;
            float r0 = EXP2F(__fmaf_rn(B0, ee, t1) + C0);
            float r1 = EXP2F(__fmaf_rn(B1, ee, t1) + C1);
            au.u[jp] = bfpack(r0, r1);
        }
        if (ch == 12 && tailInvalid) {
            au.u[0] = 0; au.u[1] = 0; au.u[2] = 0; au.u[3] = 0;
        }
#pragma unroll
        for (int nt = 0; nt < 8; nt++)
            acc[nt] = __builtin_amdgcn_mfma_f32_16x16x32_bf16(au.v, bfr[nt], acc[nt], 0, 0, 0);
    }

    // epilogue: C/D layout col n = nt*16 + (lane&15), row m = kq*4 + r
#pragma unroll
    for (int r = 0; r < 4; r++) {
        int m = kq * 4 + r;
        int e = w * 16 + m;
        float ph = sPhi[e], ps = sPsi[e], et = sEt[e];
        int pos = sPos[e];
        float vals[8];
        float s = 0.f, q2 = 0.f;
#pragma unroll
        for (int nt = 0; nt < 8; nt++) {
            int n = nt * 16 + c;
            float v = acc[nt][r] + sRow[3][n] + We[pos * 128 + n]
                    + et * sRow[0][n] + ph * sRow[1][n] + ps * sRow[2][n];
            vals[nt] = v;
            s += v;
            q2 += v * v;
        }
#pragma unroll
        for (int s2 = 1; s2 < 16; s2 <<= 1) {
            s  += __shfl_xor(s,  s2, 64);
            q2 += __shfl_xor(q2, s2, 64);
        }
        float mean = s * (1.0f / 128.0f);
        float var = q2 * (1.0f / 128.0f) - mean * mean;
        float rstd = rsqrtf(var + 1e-5f);
#pragma unroll
        for (int nt = 0; nt < 8; nt++) {
            int n = nt * 16 + c;
            out[OFF_HE + (size_t)(e0 + e) * 128 + n] =
                (vals[nt] - mean) * rstd * sRow[4][n] + sRow[5][n];
        }
    }
}

// ---------------- launch ----------------
extern "C" void kernel_launch(void* const* d_in, const int* in_sizes, int n_in,
                              void* d_out, int out_size, void* d_ws, size_t ws_size,
                              hipStream_t stream) {
    (void)in_sizes; (void)n_in; (void)out_size; (void)ws_size;
    const float* X    = (const float*)d_in[0];
    const int*   S    = (const int*)d_in[1];
    const float* BB   = (const float*)d_in[2];
    const float* SC   = (const float*)d_in[3];
    const int*   chain= (const int*)d_in[4];
    const float* mask = (const float*)d_in[5];
    const float* Wn   = (const float*)d_in[6];
    const float* bn   = (const float*)d_in[7];
    const float* gn   = (const float*)d_in[8];
    const float* betan= (const float*)d_in[9];
    const float* We   = (const float*)d_in[10];
    const float* be   = (const float*)d_in[11];
    const float* ge   = (const float*)d_in[12];
    const float* betae= (const float*)d_in[13];
    float* out = (float*)d_out;

    char* ws = (char*)d_ws;
    int*   EidxW = (int*)ws;                                  // 524288 B
    float* X5    = (float*)(ws + 524288);                     // 245760 B (ends 770048)
    short* WTf   = (short*)(ws + 770048);                     // 106496 B (ends 876544)
    float* Cax   = (float*)(ws + 876544);                     // 16384 B
    float* Cay   = (float*)(ws + 892928);                     // 16384 B
    float* Caz   = (float*)(ws + 909312);                     // 16384 B (ends 925696)

    hipLaunchKernelGGL(wconv_kernel, dim3(26), dim3(256), 0, stream, We, WTf);
    hipLaunchKernelGGL(prep_kernel, dim3((NB * NL + 255) / 256), dim3(256), 0, stream,
                       X, X5, Cax, Cay, Caz, out);
    hipLaunchKernelGGL(knn7_kernel, dim3(NB * NL / 4), dim3(256), 0, stream,
                       Cax, Cay, Caz, mask, EidxW, out);
    hipLaunchKernelGGL(node2_kernel, dim3(NB * NL / 4), dim3(256), 0, stream,
                       S, BB, SC, Wn, bn, gn, betan, out);
    hipLaunchKernelGGL(edge4_kernel, dim3(NB * NL * NK / 64), dim3(256), 0, stream,
                       X5, EidxW, chain, We, be, ge, betae, WTf, out);
}